// Round 7
// baseline (622.295 us; speedup 1.0000x reference)
//
#include <hip/hip_runtime.h>
#include <hip/hip_fp16.h>

// Fused int4-dequant GEMM (Marlin forward): C = A @ (unpack(B)-8)*s
// A: (8192, 4096) fp32   B: (512, 4096) int32 (8 nibbles along k)   s: (32, 4096) fp32
// C: (8192, 4096) fp32
//
// 128x128x64 tile, 256 threads (4 waves, 64x64/wave), mfma_f32_16x16x32_f16.
// R5 measured: 409us/disp (672 TF), MfmaUtil 30 / VALUBusy 34 / Occ 30 —
// serial stage region between the two barriers was the bottleneck.
// R6 change: DOUBLE-BUFFERED LDS (2x32KiB), ONE barrier per K-step;
// stage(kt+1) + load-issue(kt+2) + compute(kt) all in the same region so
// dequant VALU and ds_writes overlap MFMA (separate pipes). Buffers toggled
// by 2x-unrolled loop with static pointers (no runtime-indexed state).

constexpr int MDIM = 8192;
constexpr int NDIM = 4096;
constexpr int KDIM = 4096;
constexpr int BM = 128;
constexpr int BN = 128;
constexpr int BK = 64;
constexpr int THREADS = 256;
constexpr int KSTEPS = KDIM / BK;   // 64
constexpr int ABYTES = BM * BK * 2; // 16 KiB
constexpr int BBYTES = BN * BK * 2; // 16 KiB

typedef _Float16 f16x8 __attribute__((ext_vector_type(8)));
typedef float f32x4 __attribute__((ext_vector_type(4)));

__device__ __forceinline__ unsigned int pack_dq(unsigned int q, __half2 k1032,
                                                __half2 sh) {
  __half2 h = __builtin_bit_cast(__half2, q);   // (1024+nib_lo, 1024+nib_hi)
  h = __hmul2(__hsub2(h, k1032), sh);           // (nib-8)*s, sub exact
  return __builtin_bit_cast(unsigned int, h);
}

__device__ __forceinline__ unsigned int cvt2(float lo, float hi) {
  auto p = __builtin_amdgcn_cvt_pkrtz(lo, hi);  // __fp16 ext_vector(2)
  return __builtin_bit_cast(unsigned int, p);
}

__global__ __launch_bounds__(THREADS, 2)
void marlin_fused(const float* __restrict__ A, const int* __restrict__ Bq,
                  const float* __restrict__ S, float* __restrict__ C) {
  __shared__ char lds[2 * (ABYTES + BBYTES)];   // 64 KiB: A0 B0 A1 B1
  char* const As0 = lds;
  char* const Bs0 = lds + ABYTES;
  char* const As1 = lds + ABYTES + BBYTES;
  char* const Bs1 = lds + 2 * ABYTES + BBYTES;

  const int tid  = threadIdx.x;
  const int lane = tid & 63;
  const int wave = tid >> 6;
  const int wm = (wave >> 1) * 64;
  const int wn = (wave & 1) * 64;

  // XCD-aware swizzle: grid = 2048 (%8==0, bijective). n-tile in low bits so
  // each XCD keeps a contiguous A m-panel set hot in its private L2.
  const int per = gridDim.x >> 3;
  const int b   = blockIdx.x;
  const int swz = (b & 7) * per + (b >> 3);
  const int nt  = swz & 31;          // 32 n-tiles
  const int mt  = swz >> 5;          // 64 m-tiles
  const int row0 = mt * BM;
  const int col0 = nt * BN;

  f32x4 acc[4][4];
#pragma unroll
  for (int i = 0; i < 4; ++i)
#pragma unroll
    for (int j = 0; j < 4; ++j)
      acc[i][j] = f32x4{0.f, 0.f, 0.f, 0.f};

  // ---- staging constants ----
  // A: thread covers rows ar+32i (i=0..3), 8-float chunk ac.
  const int ar = tid >> 3;                 // 0..31
  const int ac = tid & 7;                  // 0..7
  const float* a_src = A + (size_t)(row0 + ar) * KDIM + ac * 8;
  const int a_off0 = (ar * 128 + ac * 16) ^ ((ar & 7) << 4);  // (ar+32i)&7==ar&7

  // B: thread covers packed row kp, 4 consecutive cols nl..nl+3.
  const int kp = tid >> 5;                 // 0..7
  const int nl = (tid & 31) * 4;           // 0..124
  const int* b_src = Bq + (size_t)kp * NDIM + col0 + nl;
  const float* s_src = S + col0 + nl;
  int bofs[4];
#pragma unroll
  for (int j = 0; j < 4; ++j) {
    const int r = nl + j;
    bofs[j] = (r * 128 + kp * 16) ^ ((((r & 7) ^ ((r >> 3) & 3))) << 4);
  }

  // fragment-read constants
  const int swzr = (lane & 7) << 4;
  const int arow = wm + (lane & 15);
  const int brow = wn + (lane & 15);
  const int kofs = (lane >> 4) << 4;

  float4 av[4][2];
  int4 bv;
  float4 sv;

  auto load_tile = [&](int kt) {
#pragma unroll
    for (int i = 0; i < 4; ++i) {
      const float* src = a_src + (size_t)i * 32 * KDIM + kt * BK;
      av[i][0] = *reinterpret_cast<const float4*>(src);
      av[i][1] = *reinterpret_cast<const float4*>(src + 4);
    }
    bv = *reinterpret_cast<const int4*>(b_src + (size_t)kt * 8 * NDIM);
    sv = *reinterpret_cast<const float4*>(s_src + (size_t)(kt >> 1) * NDIM);
  };

  auto stage_tile = [&](char* As, char* Bs) {
    // A: fp32 -> fp16, k-permuted pairs (a_j, a_{j+4}), swizzled store
#pragma unroll
    for (int i = 0; i < 4; ++i) {
      uint4 w;
      w.x = cvt2(av[i][0].x, av[i][1].x);
      w.y = cvt2(av[i][0].y, av[i][1].y);
      w.z = cvt2(av[i][0].z, av[i][1].z);
      w.w = cvt2(av[i][0].w, av[i][1].w);
      *reinterpret_cast<uint4*>(As + a_off0 + i * 32 * 128) = w;
    }
    // B: nibble unpack (0x6400 trick), scale, swizzled store
    const __half2 k1032 = __float2half2_rn(1032.0f);
    const int bw[4] = {bv.x, bv.y, bv.z, bv.w};
    const float sc[4] = {sv.x, sv.y, sv.z, sv.w};
#pragma unroll
    for (int j = 0; j < 4; ++j) {
      const unsigned int ub = (unsigned int)bw[j];
      const unsigned int m4 = 0x000F000Fu, e10 = 0x64006400u;
      const __half2 sh = __float2half2_rn(sc[j]);
      uint4 w;   // k' order (n0,n4),(n1,n5),(n2,n6),(n3,n7) — matches A perm
      w.x = pack_dq((ub & m4) | e10, k1032, sh);
      w.y = pack_dq(((ub >> 4) & m4) | e10, k1032, sh);
      w.z = pack_dq(((ub >> 8) & m4) | e10, k1032, sh);
      w.w = pack_dq(((ub >> 12) & m4) | e10, k1032, sh);
      *reinterpret_cast<uint4*>(Bs + bofs[j]) = w;
    }
  };

  auto compute_tile = [&](const char* As, const char* Bs) {
#pragma unroll
    for (int ks = 0; ks < 2; ++ks) {
      f16x8 af[4], bf[4];
#pragma unroll
      for (int mi = 0; mi < 4; ++mi) {
        const int o = ((arow + mi * 16) * 128 + ks * 64 + kofs) ^ swzr;
        af[mi] = *reinterpret_cast<const f16x8*>(As + o);
      }
#pragma unroll
      for (int ni = 0; ni < 4; ++ni) {
        const int r = brow + ni * 16;
        const int o = (r * 128 + ks * 64 + kofs) ^
                      ((((r & 7) ^ ((r >> 3) & 3))) << 4);
        bf[ni] = *reinterpret_cast<const f16x8*>(Bs + o);
      }
#pragma unroll
      for (int mi = 0; mi < 4; ++mi)
#pragma unroll
        for (int ni = 0; ni < 4; ++ni)
          acc[mi][ni] = __builtin_amdgcn_mfma_f32_16x16x32_f16(
              af[mi], bf[ni], acc[mi][ni], 0, 0, 0);
    }
  };

  // ---- prologue: tile 0 staged, tile 1 loads in flight ----
  load_tile(0);
  stage_tile(As0, Bs0);   // consumes tile-0 loads
  load_tile(1);           // in flight across the barrier
  __syncthreads();

  // ---- main loop, 2x unrolled for static buffer pointers.
  // even iter kt:   stage(kt+1)->buf1 | issue(kt+2) | compute(kt) from buf0
  // odd  iter kt+1: stage(kt+2)->buf0 | issue(kt+3) | compute(kt+1) from buf1
  // ONE barrier per iteration; WAR on each buffer separated by that barrier.
#pragma unroll 1
  for (int kt = 0; kt < KSTEPS - 2; kt += 2) {
    stage_tile(As1, Bs1);       // tile kt+1 (loads issued last iter)
    load_tile(kt + 2);
    compute_tile(As0, Bs0);     // tile kt
    __syncthreads();

    stage_tile(As0, Bs0);       // tile kt+2
    load_tile(kt + 3);
    compute_tile(As1, Bs1);     // tile kt+1
    __syncthreads();
  }

  // ---- tail: tiles 62, 63 (loads for 63 issued at kt=60 odd half) ----
  stage_tile(As1, Bs1);         // tile 63
  compute_tile(As0, Bs0);       // tile 62
  __syncthreads();
  compute_tile(As1, Bs1);       // tile 63

  // ---- epilogue: C/D layout col = lane&15, row = (lane>>4)*4 + reg ----
  const int crow = (lane >> 4) << 2;
  const int ccol = lane & 15;
#pragma unroll
  for (int mi = 0; mi < 4; ++mi)
#pragma unroll
    for (int ni = 0; ni < 4; ++ni) {
      const size_t base = (size_t)(row0 + wm + mi * 16 + crow) * NDIM
                          + (size_t)(col0 + wn + ni * 16 + ccol);
#pragma unroll
      for (int r = 0; r < 4; ++r)
        C[base + (size_t)r * NDIM] = acc[mi][ni][r];
    }
}

extern "C" void kernel_launch(void* const* d_in, const int* in_sizes, int n_in,
                              void* d_out, int out_size, void* d_ws, size_t ws_size,
                              hipStream_t stream) {
  (void)in_sizes; (void)n_in; (void)d_ws; (void)ws_size; (void)out_size;
  const float* A = (const float*)d_in[0];
  const int* Bq  = (const int*)d_in[1];
  const float* S = (const float*)d_in[2];
  float* C = (float*)d_out;
  const int grid = (MDIM / BM) * (NDIM / BN);   // 2048
  marlin_fused<<<grid, THREADS, 0, stream>>>(A, Bq, S, C);
}

// Round 10
// 516.034 us; speedup vs baseline: 1.2059x; 1.2059x over previous
//
#include <hip/hip_runtime.h>
#include <hip/hip_fp16.h>

// Fused int4-dequant GEMM (Marlin forward): C = A @ (unpack(B)-8)*s
// A: (8192,4096) fp32  B: (512,4096) int32 (8 nibbles/k)  s: (32,4096) fp32
//
// R5 measured: fused 1-buf 2-barrier 409us (MfmaUtil 30, VALU 34, Occ 30.6)
// R7 measured: fused 2-buf 1-barrier 486us (Occ 22.2 — LDS doubling cost
//   occupancy; in-order stage->compute serialized per wave). REVERTED.
// R8: move dequant/cvt OFF the hot loop. prep_a: A fp32->fp16 tiles (64MiB
// d_ws); prep_b: int4->fp16 dequant tiles (32MiB). Both pre-swizzled
// (byte ^= (row&7)<<4) and k-pair-permuted (cvt_pkrtz pairs (k,k+4) on A;
// 0x6400 nibble pairs on B — same bijection both operands => exact dot).
// gemm_f16: pure m97 structure — 8x global_load_lds(16B) + barrier +
// ds_read_b128 + 32 MFMA + barrier. No staging VALU/regs in the K-loop.
// Fallback to the measured R5 fused kernel if ws_size < 96 MiB.

constexpr int MDIM = 8192;
constexpr int NDIM = 4096;
constexpr int KDIM = 4096;
constexpr int BM = 128;
constexpr int BN = 128;
constexpr int BK = 64;
constexpr int THREADS = 256;
constexpr int KSTEPS = KDIM / BK;            // 64
constexpr int TILE_B = BM * BK * 2;          // 16384 B per tile
constexpr int MT = MDIM / BM;                // 64
constexpr int NT = NDIM / BN;                // 32
constexpr size_t AH_BYTES = (size_t)MT * KSTEPS * TILE_B;  // 64 MiB
constexpr size_t WT_BYTES = (size_t)NT * KSTEPS * TILE_B;  // 32 MiB

typedef _Float16 f16x8 __attribute__((ext_vector_type(8)));
typedef float f32x4 __attribute__((ext_vector_type(4)));
typedef __attribute__((address_space(3))) unsigned int lds_u32;
typedef const __attribute__((address_space(1))) unsigned int glb_u32;

__device__ __forceinline__ unsigned int pack_dq(unsigned int q, __half2 k1032,
                                                __half2 sh) {
  __half2 h = __builtin_bit_cast(__half2, q);   // (1024+nib_j, 1024+nib_{j+4})
  h = __hmul2(__hsub2(h, k1032), sh);           // (nib-8)*s, sub exact
  return __builtin_bit_cast(unsigned int, h);
}

__device__ __forceinline__ unsigned int cvt2(float lo, float hi) {
  auto p = __builtin_amdgcn_cvt_pkrtz(lo, hi);
  return __builtin_bit_cast(unsigned int, p);
}

// ---------------- prep passes ----------------

__global__ __launch_bounds__(THREADS)
void prep_a(const float* __restrict__ A, char* __restrict__ Ah) {
  const int bid = blockIdx.x;          // mt*64 + kt
  const int mt = bid >> 6, kt = bid & 63;
  const int t = threadIdx.x;
  const int ar = t >> 3;               // 0..31
  const int ac = t & 7;                // 0..7
  char* tile = Ah + (size_t)bid * TILE_B;
#pragma unroll
  for (int i = 0; i < 4; ++i) {
    const int r = ar + 32 * i;
    const float* src = A + (size_t)(mt * BM + r) * KDIM + kt * BK + ac * 8;
    const float4 v0 = *reinterpret_cast<const float4*>(src);
    const float4 v1 = *reinterpret_cast<const float4*>(src + 4);
    uint4 w;                           // pairs (k, k+4): matches prep_b order
    w.x = cvt2(v0.x, v1.x);
    w.y = cvt2(v0.y, v1.y);
    w.z = cvt2(v0.z, v1.z);
    w.w = cvt2(v0.w, v1.w);
    *reinterpret_cast<uint4*>(tile + ((r * 128 + ac * 16) ^ ((r & 7) << 4))) = w;
  }
}

__global__ __launch_bounds__(THREADS)
void prep_b(const int* __restrict__ Bq, const float* __restrict__ S,
            char* __restrict__ Wt) {
  const int bid = blockIdx.x;          // nt*64 + kt
  const int nt = bid >> 6, kt = bid & 63;
  const int t = threadIdx.x;
  const int kp = t >> 5;               // 0..7  (packed row within K-step)
  const int nl = (t & 31) * 4;         // 0..124
  char* tile = Wt + (size_t)bid * TILE_B;
  const int4 bv = *reinterpret_cast<const int4*>(
      Bq + (size_t)(kt * 8 + kp) * NDIM + nt * BN + nl);
  const float4 sv = *reinterpret_cast<const float4*>(
      S + (size_t)(kt >> 1) * NDIM + nt * BN + nl);  // group = (kt*8+kp)/16 = kt>>1
  const __half2 k1032 = __float2half2_rn(1032.0f);
  const int bw[4] = {bv.x, bv.y, bv.z, bv.w};
  const float sc[4] = {sv.x, sv.y, sv.z, sv.w};
#pragma unroll
  for (int j = 0; j < 4; ++j) {
    const unsigned int ub = (unsigned int)bw[j];
    const unsigned int m4 = 0x000F000Fu, e10 = 0x64006400u;
    const __half2 sh = __float2half2_rn(sc[j]);
    uint4 w;                           // k' order (n0,n4),(n1,n5),(n2,n6),(n3,n7)
    w.x = pack_dq((ub & m4) | e10, k1032, sh);
    w.y = pack_dq(((ub >> 4) & m4) | e10, k1032, sh);
    w.z = pack_dq(((ub >> 8) & m4) | e10, k1032, sh);
    w.w = pack_dq(((ub >> 12) & m4) | e10, k1032, sh);
    const int r = nl + j;
    *reinterpret_cast<uint4*>(tile + ((r * 128 + kp * 16) ^ ((r & 7) << 4))) = w;
  }
}

// ---------------- pure fp16 GEMM (m97 structure) ----------------

__global__ __launch_bounds__(THREADS, 3)
void gemm_f16(const char* __restrict__ Ah, const char* __restrict__ Wt,
              float* __restrict__ C) {
  __shared__ char lds[2 * TILE_B];     // 16 KiB A + 16 KiB B
  char* const As = lds;
  char* const Bs = lds + TILE_B;

  const int tid  = threadIdx.x;
  const int lane = tid & 63;
  const int wave = tid >> 6;
  const int wm = (wave >> 1) * 64;
  const int wn = (wave & 1) * 64;

  // XCD swizzle: grid 2048 (%8==0). XCD x gets mt range [x*8,(x+1)*8) with all
  // 32 nt per mt -> A m-panel (1 MiB) hot in that XCD's L2.
  const int per = gridDim.x >> 3;
  const int b   = blockIdx.x;
  const int swzb = (b & 7) * per + (b >> 3);
  const int nt  = swzb & 31;
  const int mt  = swzb >> 5;
  const char* atiles = Ah + (size_t)mt * KSTEPS * TILE_B;
  const char* btiles = Wt + (size_t)nt * KSTEPS * TILE_B;

  f32x4 acc[4][4];
#pragma unroll
  for (int i = 0; i < 4; ++i)
#pragma unroll
    for (int j = 0; j < 4; ++j)
      acc[i][j] = f32x4{0.f, 0.f, 0.f, 0.f};

  const int swzr = (lane & 7) << 4;
  const int arow = wm + (lane & 15);
  const int brow = wn + (lane & 15);
  const int kofs = (lane >> 4) << 4;
  const int so   = wave * 1024 + lane * 16;   // linear stage offset (src side)
  const int sd   = wave * 1024;               // wave-uniform LDS dest base

#pragma unroll 1
  for (int kt = 0; kt < KSTEPS; ++kt) {
    const char* at = atiles + (size_t)kt * TILE_B;
    const char* bt = btiles + (size_t)kt * TILE_B;
#pragma unroll
    for (int i = 0; i < 4; ++i) {
      __builtin_amdgcn_global_load_lds((glb_u32*)(at + i * 4096 + so),
                                       (lds_u32*)(As + i * 4096 + sd), 16, 0, 0);
      __builtin_amdgcn_global_load_lds((glb_u32*)(bt + i * 4096 + so),
                                       (lds_u32*)(Bs + i * 4096 + sd), 16, 0, 0);
    }
    __syncthreads();   // vmcnt(0) drain + sync: tile resident

#pragma unroll
    for (int ks = 0; ks < 2; ++ks) {
      f16x8 af[4], bf[4];
#pragma unroll
      for (int mi = 0; mi < 4; ++mi) {
        const int o = ((arow + mi * 16) * 128 + ks * 64 + kofs) ^ swzr;
        af[mi] = *reinterpret_cast<const f16x8*>(As + o);
      }
#pragma unroll
      for (int ni = 0; ni < 4; ++ni) {
        const int o = ((brow + ni * 16) * 128 + ks * 64 + kofs) ^ swzr;
        bf[ni] = *reinterpret_cast<const f16x8*>(Bs + o);
      }
#pragma unroll
      for (int mi = 0; mi < 4; ++mi)
#pragma unroll
        for (int ni = 0; ni < 4; ++ni)
          acc[mi][ni] = __builtin_amdgcn_mfma_f32_16x16x32_f16(
              af[mi], bf[ni], acc[mi][ni], 0, 0, 0);
    }
    __syncthreads();   // all reads done before next overwrite
  }

  // epilogue: C/D layout col = lane&15, row = (lane>>4)*4 + reg
  const int crow = (lane >> 4) << 2;
  const int ccol = lane & 15;
  const int row0 = mt * BM, col0 = nt * BN;
#pragma unroll
  for (int mi = 0; mi < 4; ++mi)
#pragma unroll
    for (int ni = 0; ni < 4; ++ni) {
      const size_t base = (size_t)(row0 + wm + mi * 16 + crow) * NDIM
                          + (size_t)(col0 + wn + ni * 16 + ccol);
#pragma unroll
      for (int r = 0; r < 4; ++r)
        C[base + (size_t)r * NDIM] = acc[mi][ni][r];
    }
}

// ---------------- R5 fused fallback (measured 409us) ----------------

__global__ __launch_bounds__(THREADS, 2)
void marlin_fused(const float* __restrict__ A, const int* __restrict__ Bq,
                  const float* __restrict__ S, float* __restrict__ C) {
  __shared__ char lds[2 * TILE_B];
  char* As = lds;
  char* Bs = lds + TILE_B;

  const int tid  = threadIdx.x;
  const int lane = tid & 63;
  const int wave = tid >> 6;
  const int wm = (wave >> 1) * 64;
  const int wn = (wave & 1) * 64;

  const int per = gridDim.x >> 3;
  const int b   = blockIdx.x;
  const int swz = (b & 7) * per + (b >> 3);
  const int nt  = swz & 31;
  const int mt  = swz >> 5;
  const int row0 = mt * BM;
  const int col0 = nt * BN;

  f32x4 acc[4][4];
#pragma unroll
  for (int i = 0; i < 4; ++i)
#pragma unroll
    for (int j = 0; j < 4; ++j)
      acc[i][j] = f32x4{0.f, 0.f, 0.f, 0.f};

  const int ar = tid >> 3;
  const int ac = tid & 7;
  const float* a_src = A + (size_t)(row0 + ar) * KDIM + ac * 8;
  const int a_off0 = (ar * 128 + ac * 16) ^ ((ar & 7) << 4);

  const int kp = tid >> 5;
  const int nl = (tid & 31) * 4;
  const int* b_src = Bq + (size_t)kp * NDIM + col0 + nl;
  const float* s_src = S + col0 + nl;
  int bofs[4];
#pragma unroll
  for (int j = 0; j < 4; ++j) {
    const int r = nl + j;
    bofs[j] = (r * 128 + kp * 16) ^ ((((r & 7) ^ ((r >> 3) & 3))) << 4);
  }

  const int swzr = (lane & 7) << 4;
  const int arow = wm + (lane & 15);
  const int brow = wn + (lane & 15);
  const int kofs = (lane >> 4) << 4;

  float4 av[4][2];
  int4 bv;
  float4 sv;

  auto load_tile = [&](int kt) {
#pragma unroll
    for (int i = 0; i < 4; ++i) {
      const float* src = a_src + (size_t)i * 32 * KDIM + kt * BK;
      av[i][0] = *reinterpret_cast<const float4*>(src);
      av[i][1] = *reinterpret_cast<const float4*>(src + 4);
    }
    bv = *reinterpret_cast<const int4*>(b_src + (size_t)kt * 8 * NDIM);
    sv = *reinterpret_cast<const float4*>(s_src + (size_t)(kt >> 1) * NDIM);
  };

  auto stage_tile = [&]() {
#pragma unroll
    for (int i = 0; i < 4; ++i) {
      uint4 w;
      w.x = cvt2(av[i][0].x, av[i][1].x);
      w.y = cvt2(av[i][0].y, av[i][1].y);
      w.z = cvt2(av[i][0].z, av[i][1].z);
      w.w = cvt2(av[i][0].w, av[i][1].w);
      *reinterpret_cast<uint4*>(As + a_off0 + i * 32 * 128) = w;
    }
    const __half2 k1032 = __float2half2_rn(1032.0f);
    const int bw[4] = {bv.x, bv.y, bv.z, bv.w};
    const float sc[4] = {sv.x, sv.y, sv.z, sv.w};
#pragma unroll
    for (int j = 0; j < 4; ++j) {
      const unsigned int ub = (unsigned int)bw[j];
      const unsigned int m4 = 0x000F000Fu, e10 = 0x64006400u;
      const __half2 sh = __float2half2_rn(sc[j]);
      uint4 w;
      w.x = pack_dq((ub & m4) | e10, k1032, sh);
      w.y = pack_dq(((ub >> 4) & m4) | e10, k1032, sh);
      w.z = pack_dq(((ub >> 8) & m4) | e10, k1032, sh);
      w.w = pack_dq(((ub >> 12) & m4) | e10, k1032, sh);
      *reinterpret_cast<uint4*>(Bs + bofs[j]) = w;
    }
  };

  auto compute_tile = [&]() {
#pragma unroll
    for (int ks = 0; ks < 2; ++ks) {
      f16x8 af[4], bf[4];
#pragma unroll
      for (int mi = 0; mi < 4; ++mi) {
        const int o = ((arow + mi * 16) * 128 + ks * 64 + kofs) ^ swzr;
        af[mi] = *reinterpret_cast<const f16x8*>(As + o);
      }
#pragma unroll
      for (int ni = 0; ni < 4; ++ni) {
        const int r = brow + ni * 16;
        const int o = (r * 128 + ks * 64 + kofs) ^
                      ((((r & 7) ^ ((r >> 3) & 3))) << 4);
        bf[ni] = *reinterpret_cast<const f16x8*>(Bs + o);
      }
#pragma unroll
      for (int mi = 0; mi < 4; ++mi)
#pragma unroll
        for (int ni = 0; ni < 4; ++ni)
          acc[mi][ni] = __builtin_amdgcn_mfma_f32_16x16x32_f16(
              af[mi], bf[ni], acc[mi][ni], 0, 0, 0);
    }
  };

#pragma unroll 1
  for (int kt = 0; kt < KSTEPS; ++kt) {
    load_tile(kt);
    __syncthreads();
    stage_tile();
    __syncthreads();
    compute_tile();
  }

  const int crow = (lane >> 4) << 2;
  const int ccol = lane & 15;
#pragma unroll
  for (int mi = 0; mi < 4; ++mi)
#pragma unroll
    for (int ni = 0; ni < 4; ++ni) {
      const size_t base = (size_t)(row0 + wm + mi * 16 + crow) * NDIM
                          + (size_t)(col0 + wn + ni * 16 + ccol);
#pragma unroll
      for (int r = 0; r < 4; ++r)
        C[base + (size_t)r * NDIM] = acc[mi][ni][r];
    }
}

extern "C" void kernel_launch(void* const* d_in, const int* in_sizes, int n_in,
                              void* d_out, int out_size, void* d_ws, size_t ws_size,
                              hipStream_t stream) {
  (void)in_sizes; (void)n_in; (void)out_size;
  const float* A = (const float*)d_in[0];
  const int* Bq  = (const int*)d_in[1];
  const float* S = (const float*)d_in[2];
  float* C = (float*)d_out;
  const int grid = (MDIM / BM) * (NDIM / BN);   // 2048

  if (ws_size >= AH_BYTES + WT_BYTES) {
    char* Ah = (char*)d_ws;
    char* Wt = (char*)d_ws + AH_BYTES;
    prep_a<<<MT * KSTEPS, THREADS, 0, stream>>>(A, Ah);
    prep_b<<<NT * KSTEPS, THREADS, 0, stream>>>(Bq, S, Wt);
    gemm_f16<<<grid, THREADS, 0, stream>>>(Ah, Wt, C);
  } else {
    marlin_fused<<<grid, THREADS, 0, stream>>>(A, Bq, S, C);
  }
}

// Round 12
// 461.179 us; speedup vs baseline: 1.3494x; 1.1189x over previous
//
#include <hip/hip_runtime.h>
#include <hip/hip_fp16.h>

// Fused int4-dequant GEMM (Marlin forward): C = A @ (unpack(B)-8)*s
// A: (8192,4096) fp32  B: (512,4096) int32 (8 nibbles/k)  s: (32,4096) fp32
//
// R5:  fused 1-buf 409us (MfmaUtil 30, Occ 30.6)
// R7:  fused dbuf 486us (Occ 22) REVERTED
// R10: prep(d_ws fp16 tiles) + m97-GEMM: gemm 291.5us @ 944 TF, MfmaUtil 44,
//      bank-conflict 0, FETCH 879MB (3.55 TB/s = 56% achievable) —
//      co-limited by vmcnt(0) barrier drain + 128^2 panel re-fetch.
// R11: 256^2x64 counted-vmcnt 8-phase GEMM (T3+T4+T5). 512 thr / 8 waves
//      (2Mx4N), acc[8][4], LDS 128KiB dbuf, raw s_barrier + vmcnt(8) only
//      (never 0 in loop). Half-tiles = existing 128x64 prep subtiles, so
//      prep_a/prep_b unchanged. Per tile: ph0{16 ds_read, Q00} ph1{stage
//      t+2.Bl, Q01} ph2{8 ds_read, stage t+2.Bh, Q10} ph3{stage t+2.Al+Ah,
//      Q11, vmcnt(8)}. FIFO: 8 newest = t+2's loads => t+1 resident.

constexpr int MDIM = 8192;
constexpr int NDIM = 4096;
constexpr int KDIM = 4096;
constexpr int BK = 64;
constexpr int KSTEPS = KDIM / BK;            // 64
constexpr int TILE_B = 128 * BK * 2;         // 16384 B per 128x64 subtile
constexpr size_t AH_BYTES = (size_t)64 * KSTEPS * TILE_B;  // 64 MiB
constexpr size_t WT_BYTES = (size_t)32 * KSTEPS * TILE_B;  // 32 MiB

typedef _Float16 f16x8 __attribute__((ext_vector_type(8)));
typedef float f32x4 __attribute__((ext_vector_type(4)));
typedef __attribute__((address_space(3))) unsigned int lds_u32;
typedef const __attribute__((address_space(1))) unsigned int glb_u32;

__device__ __forceinline__ unsigned int pack_dq(unsigned int q, __half2 k1032,
                                                __half2 sh) {
  __half2 h = __builtin_bit_cast(__half2, q);
  h = __hmul2(__hsub2(h, k1032), sh);
  return __builtin_bit_cast(unsigned int, h);
}

__device__ __forceinline__ unsigned int cvt2(float lo, float hi) {
  auto p = __builtin_amdgcn_cvt_pkrtz(lo, hi);
  return __builtin_bit_cast(unsigned int, p);
}

// ---------------- prep passes (unchanged from R10, measured-good) ----------

__global__ __launch_bounds__(256)
void prep_a(const float* __restrict__ A, char* __restrict__ Ah) {
  const int bid = blockIdx.x;          // m128*64 + kt
  const int mt = bid >> 6, kt = bid & 63;
  const int t = threadIdx.x;
  const int ar = t >> 3;               // 0..31
  const int ac = t & 7;                // 0..7
  char* tile = Ah + (size_t)bid * TILE_B;
#pragma unroll
  for (int i = 0; i < 4; ++i) {
    const int r = ar + 32 * i;
    const float* src = A + (size_t)(mt * 128 + r) * KDIM + kt * BK + ac * 8;
    const float4 v0 = *reinterpret_cast<const float4*>(src);
    const float4 v1 = *reinterpret_cast<const float4*>(src + 4);
    uint4 w;                           // pairs (k, k+4): matches prep_b order
    w.x = cvt2(v0.x, v1.x);
    w.y = cvt2(v0.y, v1.y);
    w.z = cvt2(v0.z, v1.z);
    w.w = cvt2(v0.w, v1.w);
    *reinterpret_cast<uint4*>(tile + ((r * 128 + ac * 16) ^ ((r & 7) << 4))) = w;
  }
}

__global__ __launch_bounds__(256)
void prep_b(const int* __restrict__ Bq, const float* __restrict__ S,
            char* __restrict__ Wt) {
  const int bid = blockIdx.x;          // n128*64 + kt
  const int nt = bid >> 6, kt = bid & 63;
  const int t = threadIdx.x;
  const int kp = t >> 5;               // 0..7
  const int nl = (t & 31) * 4;         // 0..124
  char* tile = Wt + (size_t)bid * TILE_B;
  const int4 bv = *reinterpret_cast<const int4*>(
      Bq + (size_t)(kt * 8 + kp) * NDIM + nt * 128 + nl);
  const float4 sv = *reinterpret_cast<const float4*>(
      S + (size_t)(kt >> 1) * NDIM + nt * 128 + nl);
  const __half2 k1032 = __float2half2_rn(1032.0f);
  const int bw[4] = {bv.x, bv.y, bv.z, bv.w};
  const float sc[4] = {sv.x, sv.y, sv.z, sv.w};
#pragma unroll
  for (int j = 0; j < 4; ++j) {
    const unsigned int ub = (unsigned int)bw[j];
    const unsigned int m4 = 0x000F000Fu, e10 = 0x64006400u;
    const __half2 sh = __float2half2_rn(sc[j]);
    uint4 w;
    w.x = pack_dq((ub & m4) | e10, k1032, sh);
    w.y = pack_dq(((ub >> 4) & m4) | e10, k1032, sh);
    w.z = pack_dq(((ub >> 8) & m4) | e10, k1032, sh);
    w.w = pack_dq(((ub >> 12) & m4) | e10, k1032, sh);
    const int r = nl + j;
    *reinterpret_cast<uint4*>(tile + ((r * 128 + kp * 16) ^ ((r & 7) << 4))) = w;
  }
}

// ---------------- 256^2 8-phase counted-vmcnt GEMM ----------------

__global__ __launch_bounds__(512, 1)
void gemm_f16_256(const char* __restrict__ Ah, const char* __restrict__ Wt,
                  float* __restrict__ C) {
  // buf0: A(2x16K) B(2x16K); buf1 same. 128 KiB total.
  __shared__ char lds[131072];
  char* const As0 = lds;
  char* const Bs0 = lds + 32768;
  char* const As1 = lds + 65536;
  char* const Bs1 = lds + 98304;

  const int tid  = threadIdx.x;
  const int lane = tid & 63;
  const int wave = tid >> 6;           // 0..7
  const int wr   = wave >> 2;          // 0..1  (row half)
  const int wc   = wave & 3;           // 0..3  (col quarter)

  // XCD swizzle: 512 blocks (%8==0, bijective). ntb fast within an XCD.
  const int per = gridDim.x >> 3;      // 64
  const int b   = blockIdx.x;
  const int swzb = (b & 7) * per + (b >> 3);
  const int ntb = swzb & 15;           // 16 n-tiles of 256
  const int mtb = swzb >> 4;           // 32 m-tiles of 256

  // d_ws half-tile sources: A halves = subtiles 2*mtb+h; B halves = 2*ntb+h.
  const char* aH0 = Ah + (size_t)(2 * mtb) * KSTEPS * TILE_B;
  const char* aH1 = aH0 + (size_t)KSTEPS * TILE_B;
  const char* bH0 = Wt + (size_t)(2 * ntb) * KSTEPS * TILE_B;
  const char* bH1 = bH0 + (size_t)KSTEPS * TILE_B;

  f32x4 acc[8][4];
#pragma unroll
  for (int i = 0; i < 8; ++i)
#pragma unroll
    for (int j = 0; j < 4; ++j)
      acc[i][j] = f32x4{0.f, 0.f, 0.f, 0.f};

  // fragment addressing within a 16 KiB half (128 rows x 128B, XOR-swizzled)
  const int swzr = (lane & 7) << 4;
  const int fr   = lane & 15;
  const int kofs = (lane >> 4) << 4;
  const int so   = tid * 16;           // staging src offset (per-thread)
  const int sd   = wave * 1024;        // staging LDS dest base (wave-uniform)

  f16x8 af[4][2], bf[4][2];

  auto stage_half = [&](const char* src, char* dst) {
    __builtin_amdgcn_global_load_lds((glb_u32*)(src + so),
                                     (lds_u32*)(dst + sd), 16, 0, 0);
    __builtin_amdgcn_global_load_lds((glb_u32*)(src + 8192 + so),
                                     (lds_u32*)(dst + 8192 + sd), 16, 0, 0);
  };
  auto rdA = [&](const char* aw, int mih) {
#pragma unroll
    for (int mi = 0; mi < 4; ++mi)
#pragma unroll
      for (int ks = 0; ks < 2; ++ks)
        af[mi][ks] = *reinterpret_cast<const f16x8*>(
            aw + (((mih * 64 + mi * 16 + fr) * 128 + ks * 64 + kofs) ^ swzr));
  };
  auto rdB = [&](const char* bw) {
#pragma unroll
    for (int ni = 0; ni < 4; ++ni)
#pragma unroll
      for (int ks = 0; ks < 2; ++ks)
        bf[ni][ks] = *reinterpret_cast<const f16x8*>(
            bw + ((((wc & 1) * 64 + ni * 16 + fr) * 128 + ks * 64 + kofs) ^ swzr));
  };
  auto mmaq = [&](int mih, int nih) {
#pragma unroll
    for (int mi = 0; mi < 4; ++mi)
#pragma unroll
      for (int ni = 0; ni < 2; ++ni)
#pragma unroll
        for (int ks = 0; ks < 2; ++ks)
          acc[mih * 4 + mi][nih * 2 + ni] = __builtin_amdgcn_mfma_f32_16x16x32_f16(
              af[mi][ks], bf[nih * 2 + ni][ks], acc[mih * 4 + mi][nih * 2 + ni],
              0, 0, 0);
  };

  // mode 0: steady (stage t+2, vmcnt(8)); 1: t=62 (no stage, vmcnt(0)); 2: t=63
  auto tile_step = [&](char* AC, char* BC, int t2, int mode) {
    const char* aw = AC + wr * 16384;
    const char* bw = BC + (wc >> 1) * 16384;
    // ph0
    rdA(aw, 0);
    rdB(bw);
    __builtin_amdgcn_s_barrier();
    __builtin_amdgcn_s_setprio(1);
    mmaq(0, 0);
    __builtin_amdgcn_s_setprio(0);
    __builtin_amdgcn_s_barrier();
    // ph1
    if (mode == 0) stage_half(bH0 + (size_t)t2 * TILE_B, BC);
    __builtin_amdgcn_s_barrier();
    __builtin_amdgcn_s_setprio(1);
    mmaq(0, 1);
    __builtin_amdgcn_s_setprio(0);
    __builtin_amdgcn_s_barrier();
    // ph2
    rdA(aw, 1);
    if (mode == 0) stage_half(bH1 + (size_t)t2 * TILE_B, BC + 16384);
    __builtin_amdgcn_s_barrier();
    __builtin_amdgcn_s_setprio(1);
    mmaq(1, 0);
    __builtin_amdgcn_s_setprio(0);
    __builtin_amdgcn_s_barrier();
    // ph3
    if (mode == 0) {
      stage_half(aH0 + (size_t)t2 * TILE_B, AC);
      stage_half(aH1 + (size_t)t2 * TILE_B, AC + 16384);
    }
    __builtin_amdgcn_s_barrier();
    __builtin_amdgcn_s_setprio(1);
    mmaq(1, 1);
    __builtin_amdgcn_s_setprio(0);
    if (mode == 0) {
      asm volatile("s_waitcnt vmcnt(8)" ::: "memory");   // t+1 resident
      __builtin_amdgcn_sched_barrier(0);
    } else if (mode == 1) {
      asm volatile("s_waitcnt vmcnt(0)" ::: "memory");   // t63 resident
      __builtin_amdgcn_sched_barrier(0);
    }
    __builtin_amdgcn_s_barrier();
  };

  // prologue: t0 -> buf0, t1 -> buf1; confirm t0 (8 newest = t1's loads)
  stage_half(aH0, As0); stage_half(aH1, As0 + 16384);
  stage_half(bH0, Bs0); stage_half(bH1, Bs0 + 16384);
  stage_half(aH0 + TILE_B, As1); stage_half(aH1 + TILE_B, As1 + 16384);
  stage_half(bH0 + TILE_B, Bs1); stage_half(bH1 + TILE_B, Bs1 + 16384);
  asm volatile("s_waitcnt vmcnt(8)" ::: "memory");
  __builtin_amdgcn_sched_barrier(0);
  __builtin_amdgcn_s_barrier();

#pragma unroll 1
  for (int t = 0; t < KSTEPS - 2; t += 2) {
    tile_step(As0, Bs0, t + 2, 0);
    tile_step(As1, Bs1, t + 3, 0);
  }
  tile_step(As0, Bs0, 0, 1);   // t=62
  tile_step(As1, Bs1, 0, 2);   // t=63

  // epilogue: C/D col = lane&15, row = (lane>>4)*4 + reg
  const int crow = (lane >> 4) << 2;
  const int ccol = lane & 15;
  const int row0 = mtb * 256 + wr * 128;
  const int col0 = ntb * 256 + wc * 64;
#pragma unroll
  for (int mi = 0; mi < 8; ++mi)
#pragma unroll
    for (int ni = 0; ni < 4; ++ni) {
      const size_t base = (size_t)(row0 + mi * 16 + crow) * NDIM
                          + (size_t)(col0 + ni * 16 + ccol);
#pragma unroll
      for (int r = 0; r < 4; ++r)
        C[base + (size_t)r * NDIM] = acc[mi][ni][r];
    }
}

// ---------------- R5 fused fallback (measured 409us) ----------------

__global__ __launch_bounds__(256, 2)
void marlin_fused(const float* __restrict__ A, const int* __restrict__ Bq,
                  const float* __restrict__ S, float* __restrict__ C) {
  __shared__ char lds[2 * TILE_B];
  char* As = lds;
  char* Bs = lds + TILE_B;

  const int tid  = threadIdx.x;
  const int lane = tid & 63;
  const int wave = tid >> 6;
  const int wm = (wave >> 1) * 64;
  const int wn = (wave & 1) * 64;

  const int per = gridDim.x >> 3;
  const int b   = blockIdx.x;
  const int swz = (b & 7) * per + (b >> 3);
  const int nt  = swz & 31;
  const int mt  = swz >> 5;
  const int row0 = mt * 128;
  const int col0 = nt * 128;

  f32x4 acc[4][4];
#pragma unroll
  for (int i = 0; i < 4; ++i)
#pragma unroll
    for (int j = 0; j < 4; ++j)
      acc[i][j] = f32x4{0.f, 0.f, 0.f, 0.f};

  const int ar = tid >> 3;
  const int ac = tid & 7;
  const float* a_src = A + (size_t)(row0 + ar) * KDIM + ac * 8;
  const int a_off0 = (ar * 128 + ac * 16) ^ ((ar & 7) << 4);

  const int kp = tid >> 5;
  const int nl = (tid & 31) * 4;
  const int* b_src = Bq + (size_t)kp * NDIM + col0 + nl;
  const float* s_src = S + col0 + nl;
  int bofs[4];
#pragma unroll
  for (int j = 0; j < 4; ++j) {
    const int r = nl + j;
    bofs[j] = (r * 128 + kp * 16) ^ ((((r & 7) ^ ((r >> 3) & 3))) << 4);
  }

  const int swzr = (lane & 7) << 4;
  const int arow = wm + (lane & 15);
  const int brow = wn + (lane & 15);
  const int kofs = (lane >> 4) << 4;

  float4 av[4][2];
  int4 bv;
  float4 sv;

  auto load_tile = [&](int kt) {
#pragma unroll
    for (int i = 0; i < 4; ++i) {
      const float* src = a_src + (size_t)i * 32 * KDIM + kt * BK;
      av[i][0] = *reinterpret_cast<const float4*>(src);
      av[i][1] = *reinterpret_cast<const float4*>(src + 4);
    }
    bv = *reinterpret_cast<const int4*>(b_src + (size_t)kt * 8 * NDIM);
    sv = *reinterpret_cast<const float4*>(s_src + (size_t)(kt >> 1) * NDIM);
  };

  auto stage_tile = [&]() {
#pragma unroll
    for (int i = 0; i < 4; ++i) {
      uint4 w;
      w.x = cvt2(av[i][0].x, av[i][1].x);
      w.y = cvt2(av[i][0].y, av[i][1].y);
      w.z = cvt2(av[i][0].z, av[i][1].z);
      w.w = cvt2(av[i][0].w, av[i][1].w);
      *reinterpret_cast<uint4*>(As + a_off0 + i * 32 * 128) = w;
    }
    const __half2 k1032 = __float2half2_rn(1032.0f);
    const int bw[4] = {bv.x, bv.y, bv.z, bv.w};
    const float sc[4] = {sv.x, sv.y, sv.z, sv.w};
#pragma unroll
    for (int j = 0; j < 4; ++j) {
      const unsigned int ub = (unsigned int)bw[j];
      const unsigned int m4 = 0x000F000Fu, e10 = 0x64006400u;
      const __half2 sh = __float2half2_rn(sc[j]);
      uint4 w;
      w.x = pack_dq((ub & m4) | e10, k1032, sh);
      w.y = pack_dq(((ub >> 4) & m4) | e10, k1032, sh);
      w.z = pack_dq(((ub >> 8) & m4) | e10, k1032, sh);
      w.w = pack_dq(((ub >> 12) & m4) | e10, k1032, sh);
      *reinterpret_cast<uint4*>(Bs + bofs[j]) = w;
    }
  };

  auto compute_tile = [&]() {
#pragma unroll
    for (int ks = 0; ks < 2; ++ks) {
      f16x8 af[4], bf[4];
#pragma unroll
      for (int mi = 0; mi < 4; ++mi) {
        const int o = ((arow + mi * 16) * 128 + ks * 64 + kofs) ^ swzr;
        af[mi] = *reinterpret_cast<const f16x8*>(As + o);
      }
#pragma unroll
      for (int ni = 0; ni < 4; ++ni) {
        const int r = brow + ni * 16;
        const int o = (r * 128 + ks * 64 + kofs) ^
                      ((((r & 7) ^ ((r >> 3) & 3))) << 4);
        bf[ni] = *reinterpret_cast<const f16x8*>(Bs + o);
      }
#pragma unroll
      for (int mi = 0; mi < 4; ++mi)
#pragma unroll
        for (int ni = 0; ni < 4; ++ni)
          acc[mi][ni] = __builtin_amdgcn_mfma_f32_16x16x32_f16(
              af[mi], bf[ni], acc[mi][ni], 0, 0, 0);
    }
  };

#pragma unroll 1
  for (int kt = 0; kt < KSTEPS; ++kt) {
    load_tile(kt);
    __syncthreads();
    stage_tile();
    __syncthreads();
    compute_tile();
  }

  const int crow = (lane >> 4) << 2;
  const int ccol = lane & 15;
#pragma unroll
  for (int mi = 0; mi < 4; ++mi)
#pragma unroll
    for (int ni = 0; ni < 4; ++ni) {
      const size_t base = (size_t)(row0 + wm + mi * 16 + crow) * NDIM
                          + (size_t)(col0 + wn + ni * 16 + ccol);
#pragma unroll
      for (int r = 0; r < 4; ++r)
        C[base + (size_t)r * NDIM] = acc[mi][ni][r];
    }
}

extern "C" void kernel_launch(void* const* d_in, const int* in_sizes, int n_in,
                              void* d_out, int out_size, void* d_ws, size_t ws_size,
                              hipStream_t stream) {
  (void)in_sizes; (void)n_in; (void)out_size;
  const float* A = (const float*)d_in[0];
  const int* Bq  = (const int*)d_in[1];
  const float* S = (const float*)d_in[2];
  float* C = (float*)d_out;

  if (ws_size >= AH_BYTES + WT_BYTES) {
    char* Ah = (char*)d_ws;
    char* Wt = (char*)d_ws + AH_BYTES;
    prep_a<<<64 * KSTEPS, 256, 0, stream>>>(A, Ah);
    prep_b<<<32 * KSTEPS, 256, 0, stream>>>(Bq, S, Wt);
    gemm_f16_256<<<(MDIM / 256) * (NDIM / 256), 512, 0, stream>>>(Ah, Wt, C);
  } else {
    marlin_fused<<<2048, 256, 0, stream>>>(A, Bq, S, C);
  }
}